// Round 1
// baseline (617.265 us; speedup 1.0000x reference)
//
#include <hip/hip_runtime.h>

#define T_SEQ 4096
#define DMODEL 1024
#define HEAD 64
#define NBATCH 4

#define QT 32      // q rows per tile
#define KT 64      // keys per tile
#define LDST 68    // LDS row stride (floats), 68*4B = 272B (16B aligned, odd*4 banks)

// ---------------- Kernel 1: QKV projection ----------------
// grid = (B*T)/32 = 512 blocks, 256 threads.
// Wave w handles rows r0..r0+7; lane = output column (0..63).
__global__ __launch_bounds__(256) void qkv_proj(
    const float* __restrict__ x,
    const float* __restrict__ Wq, const float* __restrict__ bq,
    const float* __restrict__ Wk, const float* __restrict__ bk,
    const float* __restrict__ Wv, const float* __restrict__ bv,
    float* __restrict__ qo, float* __restrict__ ko, float* __restrict__ vo)
{
    const int lane = threadIdx.x & 63;
    // force wave-uniformity so x reads become scalar (s_load) loads
    const int w = __builtin_amdgcn_readfirstlane((int)(threadIdx.x >> 6));
    const long r0 = (long)blockIdx.x * 32 + (long)w * 8;

    float aq[8], ak[8], av[8];
    const float bqv = bq[lane], bkv = bk[lane], bvv = bv[lane];
#pragma unroll
    for (int i = 0; i < 8; ++i) { aq[i] = bqv; ak[i] = bkv; av[i] = bvv; }

    const float* xrow = x + r0 * DMODEL;
    for (int k4 = 0; k4 < DMODEL / 4; ++k4) {
        float4 xv[8];
#pragma unroll
        for (int i = 0; i < 8; ++i)
            xv[i] = *(const float4*)(xrow + (long)i * DMODEL + k4 * 4);
#pragma unroll
        for (int e = 0; e < 4; ++e) {
            const int kk = k4 * 4 + e;
            const float wq = Wq[kk * HEAD + lane];
            const float wk = Wk[kk * HEAD + lane];
            const float wv = Wv[kk * HEAD + lane];
#pragma unroll
            for (int i = 0; i < 8; ++i) {
                const float xe = (e == 0) ? xv[i].x : (e == 1) ? xv[i].y
                                : (e == 2) ? xv[i].z : xv[i].w;
                aq[i] = fmaf(xe, wq, aq[i]);
                ak[i] = fmaf(xe, wk, ak[i]);
                av[i] = fmaf(xe, wv, av[i]);
            }
        }
    }
#pragma unroll
    for (int i = 0; i < 8; ++i) {
        qo[(r0 + i) * HEAD + lane] = aq[i];
        ko[(r0 + i) * HEAD + lane] = ak[i];
        vo[(r0 + i) * HEAD + lane] = av[i];
    }
}

// ---------------- Kernel 2: causal flash attention ----------------
// grid = (64, B). Block p handles q-tiles {p, 127-p} (causal load balance).
// 256 threads = 4 waves.
__global__ __launch_bounds__(256) void flash_attn(
    const float* __restrict__ q, const float* __restrict__ k,
    const float* __restrict__ v, float* __restrict__ out)
{
    __shared__ __align__(16) float q_s[QT][LDST];
    __shared__ __align__(16) float k_s[KT][LDST];
    __shared__ __align__(16) float vt_s[HEAD][LDST];  // [dim][key]
    __shared__ __align__(16) float p_s[QT][LDST];
    __shared__ float m_l[QT], l_l[QT], a_l[QT];

    const int t    = threadIdx.x;
    const int b    = blockIdx.y;
    const int pair = blockIdx.x;          // 0..63
    const int lane = t & 63;
    const int tx   = t & 15;              // phase-1 col group
    const int ty   = t >> 4;              // phase-1 row group (0..15)
    const int rg   = t >> 6;              // phase-2 row group (0..3)

    const float scale = 0.03125f;         // 1/sqrt(1024)
    const long  base  = (long)b * T_SEQ * HEAD;

    for (int half = 0; half < 2; ++half) {
        const int qt    = half ? (127 - pair) : pair;
        const int qrow0 = qt * QT;
        const int nkt   = (qrow0 + QT + KT - 1) / KT;

        __syncthreads();   // protect LDS from previous half
        if (t < QT) { m_l[t] = -1e30f; l_l[t] = 0.f; }
        // stage Q tile (32 x 64 floats = 512 float4)
#pragma unroll
        for (int c = 0; c < 2; ++c) {
            const int lin = c * 256 + t;
            const int row = lin >> 4, d4 = lin & 15;
            *(float4*)&q_s[row][d4 * 4] =
                *(const float4*)&q[base + (long)(qrow0 + row) * HEAD + d4 * 4];
        }
        float o[8];
#pragma unroll
        for (int i = 0; i < 8; ++i) o[i] = 0.f;

        for (int kt = 0; kt < nkt; ++kt) {
            const int key0 = kt * KT;
            __syncthreads();
            // stage K tile and V tile (V transposed)
#pragma unroll
            for (int c = 0; c < 4; ++c) {
                const int lin = c * 256 + t;           // 0..1023
                const int key = lin >> 4, d4 = lin & 15;
                const long g = base + (long)(key0 + key) * HEAD + d4 * 4;
                float4 kv4 = *(const float4*)&k[g];
                *(float4*)&k_s[key][d4 * 4] = kv4;
                float4 vv4 = *(const float4*)&v[g];
                vt_s[d4 * 4 + 0][key] = vv4.x;
                vt_s[d4 * 4 + 1][key] = vv4.y;
                vt_s[d4 * 4 + 2][key] = vv4.z;
                vt_s[d4 * 4 + 3][key] = vv4.w;
            }
            __syncthreads();

            // ---- phase 1: S = Q K^T (rows ty*2+{0,1}, cols tx+16j) ----
            float s[2][4];
#pragma unroll
            for (int i = 0; i < 2; ++i)
#pragma unroll
                for (int j = 0; j < 4; ++j) s[i][j] = 0.f;
            const int row0 = ty * 2;
#pragma unroll 4
            for (int d4 = 0; d4 < 16; ++d4) {
                const float4 q0 = *(const float4*)&q_s[row0][d4 * 4];
                const float4 q1 = *(const float4*)&q_s[row0 + 1][d4 * 4];
#pragma unroll
                for (int j = 0; j < 4; ++j) {
                    const float4 kv = *(const float4*)&k_s[tx + 16 * j][d4 * 4];
                    s[0][j] += q0.x * kv.x + q0.y * kv.y + q0.z * kv.z + q0.w * kv.w;
                    s[1][j] += q1.x * kv.x + q1.y * kv.y + q1.z * kv.z + q1.w * kv.w;
                }
            }
            // mask + scale + tile max
            float mt[2] = { -1e30f, -1e30f };
#pragma unroll
            for (int i = 0; i < 2; ++i) {
                const int qrow = qrow0 + row0 + i;
#pragma unroll
                for (int j = 0; j < 4; ++j) {
                    const int key = key0 + tx + 16 * j;
                    const float val = (key <= qrow) ? s[i][j] * scale : -1e30f;
                    s[i][j] = val;
                    mt[i] = fmaxf(mt[i], val);
                }
            }
#pragma unroll
            for (int m = 1; m <= 8; m <<= 1) {
                mt[0] = fmaxf(mt[0], __shfl_xor(mt[0], m));
                mt[1] = fmaxf(mt[1], __shfl_xor(mt[1], m));
            }
            // online softmax update
#pragma unroll
            for (int i = 0; i < 2; ++i) {
                const int row = row0 + i;
                const float mp = m_l[row];                 // broadcast read
                const float mn = fmaxf(mp, mt[i]);
                const float al = __expf(mp - mn);
                float ssum = 0.f;
#pragma unroll
                for (int j = 0; j < 4; ++j) {
                    const float p = __expf(s[i][j] - mn);
                    p_s[row][tx + 16 * j] = p;
                    ssum += p;
                }
#pragma unroll
                for (int m = 1; m <= 8; m <<= 1) ssum += __shfl_xor(ssum, m);
                if (tx == 0) {
                    m_l[row] = mn;
                    a_l[row] = al;
                    l_l[row] = l_l[row] * al + ssum;
                }
            }
            __syncthreads();

            // ---- phase 2: O = O*alpha + P V (col = lane, rows rg*8+i) ----
            const int r0p = rg * 8;
#pragma unroll
            for (int i = 0; i < 8; ++i) o[i] *= a_l[r0p + i];
#pragma unroll 4
            for (int j4 = 0; j4 < 16; ++j4) {
                const float4 vv = *(const float4*)&vt_s[lane][j4 * 4];
#pragma unroll
                for (int i = 0; i < 8; ++i) {
                    const float4 pv = *(const float4*)&p_s[r0p + i][j4 * 4];
                    o[i] += pv.x * vv.x + pv.y * vv.y + pv.z * vv.z + pv.w * vv.w;
                }
            }
        }
        // epilogue: normalize and store (l_l final since barrier before phase 2)
#pragma unroll
        for (int i = 0; i < 8; ++i) {
            const int row = rg * 8 + i;
            out[base + (long)(qrow0 + row) * HEAD + lane] = o[i] / l_l[row];
        }
    }
}

extern "C" void kernel_launch(void* const* d_in, const int* in_sizes, int n_in,
                              void* d_out, int out_size, void* d_ws, size_t ws_size,
                              hipStream_t stream) {
    const float* x  = (const float*)d_in[0];
    const float* Wq = (const float*)d_in[1];
    const float* bq = (const float*)d_in[2];
    const float* Wk = (const float*)d_in[3];
    const float* bk = (const float*)d_in[4];
    const float* Wv = (const float*)d_in[5];
    const float* bv = (const float*)d_in[6];
    float* outp = (float*)d_out;

    const long nTok = (long)NBATCH * T_SEQ;          // 16384
    float* qw = (float*)d_ws;                        // 4 MB
    float* kw = qw + nTok * HEAD;                    // 4 MB
    float* vw = kw + nTok * HEAD;                    // 4 MB

    qkv_proj<<<dim3(nTok / 32), dim3(256), 0, stream>>>(
        x, Wq, bq, Wk, bk, Wv, bv, qw, kw, vw);

    flash_attn<<<dim3(64, NBATCH), dim3(256), 0, stream>>>(qw, kw, vw, outp);
}

// Round 2
// 276.980 us; speedup vs baseline: 2.2285x; 2.2285x over previous
//
#include <hip/hip_runtime.h>

#define T_SEQ 4096
#define DMODEL 1024
#define HEAD 64
#define NBATCH 4

typedef __attribute__((ext_vector_type(8))) short bf16x8;
typedef __attribute__((ext_vector_type(4))) float f32x4;

__device__ __forceinline__ unsigned short f2bf(float f) {
    unsigned int b = __float_as_uint(f);
    unsigned int r = b + 0x7FFFu + ((b >> 16) & 1u);
    return (unsigned short)(r >> 16);
}

// ---------------- Kernel 1: QKV projection (fp32 in, bf16 out; V transposed) --
// grid = 16384/16 = 1024 blocks, 256 threads. Wave w: rows r0..r0+3, lane = col.
__global__ __launch_bounds__(256) void qkv_proj(
    const float* __restrict__ x,
    const float* __restrict__ Wq, const float* __restrict__ bq,
    const float* __restrict__ Wk, const float* __restrict__ bk,
    const float* __restrict__ Wv, const float* __restrict__ bv,
    unsigned short* __restrict__ qo, unsigned short* __restrict__ ko,
    unsigned short* __restrict__ vt)
{
    const int lane = threadIdx.x & 63;
    const int w = __builtin_amdgcn_readfirstlane((int)(threadIdx.x >> 6));
    const long r0 = (long)blockIdx.x * 16 + (long)w * 4;

    float aq[4], ak[4], av[4];
    const float bqv = bq[lane], bkv = bk[lane], bvv = bv[lane];
#pragma unroll
    for (int i = 0; i < 4; ++i) { aq[i] = bqv; ak[i] = bkv; av[i] = bvv; }

    const float* xrow = x + r0 * DMODEL;
    for (int k4 = 0; k4 < DMODEL / 4; ++k4) {
        float4 xv[4];
#pragma unroll
        for (int i = 0; i < 4; ++i)
            xv[i] = *(const float4*)(xrow + (long)i * DMODEL + k4 * 4);
#pragma unroll
        for (int e = 0; e < 4; ++e) {
            const int kk = k4 * 4 + e;
            const float wq = Wq[kk * HEAD + lane];
            const float wk = Wk[kk * HEAD + lane];
            const float wv = Wv[kk * HEAD + lane];
#pragma unroll
            for (int i = 0; i < 4; ++i) {
                const float xe = (e == 0) ? xv[i].x : (e == 1) ? xv[i].y
                                : (e == 2) ? xv[i].z : xv[i].w;
                aq[i] = fmaf(xe, wq, aq[i]);
                ak[i] = fmaf(xe, wk, ak[i]);
                av[i] = fmaf(xe, wv, av[i]);
            }
        }
    }
#pragma unroll
    for (int i = 0; i < 4; ++i) {
        qo[(r0 + i) * HEAD + lane] = f2bf(aq[i]);
        ko[(r0 + i) * HEAD + lane] = f2bf(ak[i]);
    }
    // vt[b][dim][t] : 4 bf16 contiguous per lane (t multiple of 4 -> 8B aligned)
    const int b  = (int)(r0 >> 12);
    const int tl = (int)(r0 & 4095);
    unsigned int p0 = (unsigned)f2bf(av[0]) | ((unsigned)f2bf(av[1]) << 16);
    unsigned int p1 = (unsigned)f2bf(av[2]) | ((unsigned)f2bf(av[3]) << 16);
    uint2 pv; pv.x = p0; pv.y = p1;
    *(uint2*)&vt[((long)(b * HEAD + lane)) * T_SEQ + tl] = pv;
}

// ---------------- Kernel 2: causal flash attention, bf16 MFMA ----------------
// grid = 512 (128 q-tiles x 4 batches, heavy tiles first), 256 threads.
// wave w: strip = w>>1 (16 q-rows), half = w&1 (64 of 128 staged keys).
#define QT 32
#define SKT 128
#define KSS 72      // k_s row stride (bf16): 144B -> 2-way bank alias (free)
#define VTS 136     // vt_s row stride: 272B -> 2-way
#define QSS 72
#define PSS 72

__global__ __launch_bounds__(256) void flash_attn(
    const unsigned short* __restrict__ qg,
    const unsigned short* __restrict__ kg,
    const unsigned short* __restrict__ vtg,
    float* __restrict__ out)
{
    __shared__ __align__(16) unsigned short k_s[SKT * KSS];   // 18432 B
    __shared__ __align__(16) unsigned short vt_s[HEAD * VTS]; // 17408 B
    __shared__ __align__(16) unsigned short q_s[QT * QSS];    //  4608 B
    __shared__ __align__(16) unsigned short p_s[4 * 16 * PSS];//  9216 B

    const int t     = threadIdx.x;
    const int n     = blockIdx.x;
    const int tile  = 127 - (n >> 2);      // heavy first
    const int b     = n & 3;
    const int qrow0 = tile * QT;
    const int lane  = t & 63;
    const int l15   = lane & 15;
    const int quad  = lane >> 4;
    const int w     = __builtin_amdgcn_readfirstlane(t >> 6);
    const int strip = w >> 1;
    const int half  = w & 1;
    const long bbase = (long)b * T_SEQ;
    const float scale = 0.03125f;          // 1/sqrt(1024)

    // stage Q tile (32 x 64 bf16) : exactly 256 chunks of 16B
    {
        const int row = t >> 3, d8 = t & 7;
        *(uint4*)&q_s[row * QSS + d8 * 8] =
            *(const uint4*)&qg[(bbase + qrow0 + row) * HEAD + d8 * 8];
    }
    __syncthreads();

    bf16x8 aq0 = *(const bf16x8*)&q_s[(strip * 16 + l15) * QSS + quad * 8];
    bf16x8 aq1 = *(const bf16x8*)&q_s[(strip * 16 + l15) * QSS + 32 + quad * 8];

    f32x4 o[4];
#pragma unroll
    for (int dt = 0; dt < 4; ++dt) o[dt] = (f32x4){0.f, 0.f, 0.f, 0.f};
    float mrun[4], lrun[4];
#pragma unroll
    for (int r = 0; r < 4; ++r) { mrun[r] = -1e30f; lrun[r] = 0.f; }

    const int nkt = (qrow0 + QT + SKT - 1) / SKT;
    const int qrow_base = qrow0 + strip * 16;
    unsigned short* ps = p_s + w * 16 * PSS;

    for (int kt = 0; kt < nkt; ++kt) {
        const int key0 = kt * SKT;
        __syncthreads();
        // stage K supertile (128 keys x 64 dims)
#pragma unroll
        for (int c = 0; c < 4; ++c) {
            const int lin = c * 256 + t;
            const int row = lin >> 3, d8 = lin & 7;
            int gk = key0 + row; if (gk > T_SEQ - 1) gk = T_SEQ - 1;
            *(uint4*)&k_s[row * KSS + d8 * 8] =
                *(const uint4*)&kg[(bbase + gk) * HEAD + d8 * 8];
        }
        // stage Vt supertile (64 dims x 128 keys)
#pragma unroll
        for (int c = 0; c < 4; ++c) {
            const int lin = c * 256 + t;
            const int dim = lin >> 4, k8 = lin & 15;
            int koff = key0 + k8 * 8; if (koff > T_SEQ - 8) koff = T_SEQ - 8;
            *(uint4*)&vt_s[dim * VTS + k8 * 8] =
                *(const uint4*)&vtg[((long)(b * HEAD + dim)) * T_SEQ + koff];
        }
        __syncthreads();

        const int keyw = key0 + half * 64;
        if (keyw <= qrow0 + QT - 1) {
            // ---- S = Q K^T : 4 n-tiles of 16 keys, K accumulated over 2x32
            f32x4 s[4];
#pragma unroll
            for (int nt = 0; nt < 4; ++nt) s[nt] = (f32x4){0.f, 0.f, 0.f, 0.f};
#pragma unroll
            for (int nt = 0; nt < 4; ++nt) {
                bf16x8 bk0 = *(const bf16x8*)&k_s[(half * 64 + nt * 16 + l15) * KSS + quad * 8];
                bf16x8 bk1 = *(const bf16x8*)&k_s[(half * 64 + nt * 16 + l15) * KSS + 32 + quad * 8];
                s[nt] = __builtin_amdgcn_mfma_f32_16x16x32_bf16(aq0, bk0, s[nt], 0, 0, 0);
                s[nt] = __builtin_amdgcn_mfma_f32_16x16x32_bf16(aq1, bk1, s[nt], 0, 0, 0);
            }
            // ---- mask + scale + row max (rows quad*4+r, within-quad shuffle)
            float mt[4] = {-1e30f, -1e30f, -1e30f, -1e30f};
#pragma unroll
            for (int nt = 0; nt < 4; ++nt)
#pragma unroll
                for (int r = 0; r < 4; ++r) {
                    const int key  = keyw + nt * 16 + l15;
                    const int qrow = qrow_base + quad * 4 + r;
                    const float val = (key <= qrow) ? s[nt][r] * scale : -1e30f;
                    s[nt][r] = val;
                    mt[r] = fmaxf(mt[r], val);
                }
#pragma unroll
            for (int msk = 1; msk <= 8; msk <<= 1)
#pragma unroll
                for (int r = 0; r < 4; ++r)
                    mt[r] = fmaxf(mt[r], __shfl_xor(mt[r], msk));
            // ---- online softmax update (register-only state, per quad-row)
            float al[4], psum[4];
#pragma unroll
            for (int r = 0; r < 4; ++r) {
                const float mn = fmaxf(mrun[r], mt[r]);
                al[r] = __expf(mrun[r] - mn);
                mrun[r] = mn;
                psum[r] = 0.f;
            }
#pragma unroll
            for (int nt = 0; nt < 4; ++nt)
#pragma unroll
                for (int r = 0; r < 4; ++r) {
                    const float p = (s[nt][r] > -0.9e30f) ? __expf(s[nt][r] - mrun[r]) : 0.f;
                    psum[r] += p;
                    ps[(quad * 4 + r) * PSS + nt * 16 + l15] = f2bf(p);
                }
#pragma unroll
            for (int msk = 1; msk <= 8; msk <<= 1)
#pragma unroll
                for (int r = 0; r < 4; ++r)
                    psum[r] += __shfl_xor(psum[r], msk);
#pragma unroll
            for (int r = 0; r < 4; ++r) lrun[r] = lrun[r] * al[r] + psum[r];
            // ---- rescale O, then O += P V
#pragma unroll
            for (int dt = 0; dt < 4; ++dt)
#pragma unroll
                for (int r = 0; r < 4; ++r) o[dt][r] *= al[r];
            __builtin_amdgcn_wave_barrier();  // order ds_write(p) before ds_read
            bf16x8 ap0 = *(const bf16x8*)&ps[l15 * PSS + quad * 8];
            bf16x8 ap1 = *(const bf16x8*)&ps[l15 * PSS + 32 + quad * 8];
#pragma unroll
            for (int dt = 0; dt < 4; ++dt) {
                bf16x8 bv0 = *(const bf16x8*)&vt_s[(dt * 16 + l15) * VTS + half * 64 + quad * 8];
                bf16x8 bv1 = *(const bf16x8*)&vt_s[(dt * 16 + l15) * VTS + half * 64 + 32 + quad * 8];
                o[dt] = __builtin_amdgcn_mfma_f32_16x16x32_bf16(ap0, bv0, o[dt], 0, 0, 0);
                o[dt] = __builtin_amdgcn_mfma_f32_16x16x32_bf16(ap1, bv1, o[dt], 0, 0, 0);
            }
        }
    }

    // ---- merge the two key-halves per strip (reuse staging LDS) ----
    __syncthreads();
    float* o_l  = (float*)k_s;    // [2][16][64] fp32 = 8 KB
    float* ml_l = (float*)vt_s;   // m at [0..31], l at [32..63]
    if (half == 1) {
#pragma unroll
        for (int dt = 0; dt < 4; ++dt)
#pragma unroll
            for (int r = 0; r < 4; ++r)
                o_l[(strip * 16 + quad * 4 + r) * HEAD + dt * 16 + l15] = o[dt][r];
        if (l15 == 0)
#pragma unroll
            for (int r = 0; r < 4; ++r) {
                ml_l[strip * 16 + quad * 4 + r]      = mrun[r];
                ml_l[32 + strip * 16 + quad * 4 + r] = lrun[r];
            }
    }
    __syncthreads();
    if (half == 0) {
        float w1s[4], w2s[4];
#pragma unroll
        for (int r = 0; r < 4; ++r) {
            const int rr = strip * 16 + quad * 4 + r;
            const float m2 = ml_l[rr], l2 = ml_l[32 + rr];
            const float M  = fmaxf(mrun[r], m2);
            const float w1 = __expf(mrun[r] - M), w2 = __expf(m2 - M);
            const float inv = 1.f / (w1 * lrun[r] + w2 * l2);
            w1s[r] = w1 * inv; w2s[r] = w2 * inv;
        }
#pragma unroll
        for (int dt = 0; dt < 4; ++dt)
#pragma unroll
            for (int r = 0; r < 4; ++r) {
                const int rr = strip * 16 + quad * 4 + r;
                const float o2 = o_l[rr * HEAD + dt * 16 + l15];
                out[(bbase + qrow0 + rr) * HEAD + dt * 16 + l15] =
                    o[dt][r] * w1s[r] + o2 * w2s[r];
            }
    }
}

extern "C" void kernel_launch(void* const* d_in, const int* in_sizes, int n_in,
                              void* d_out, int out_size, void* d_ws, size_t ws_size,
                              hipStream_t stream) {
    const float* x  = (const float*)d_in[0];
    const float* Wq = (const float*)d_in[1];
    const float* bq = (const float*)d_in[2];
    const float* Wk = (const float*)d_in[3];
    const float* bk = (const float*)d_in[4];
    const float* Wv = (const float*)d_in[5];
    const float* bv = (const float*)d_in[6];
    float* outp = (float*)d_out;

    const long nTok = (long)NBATCH * T_SEQ;              // 16384
    unsigned short* qw  = (unsigned short*)d_ws;         // 2 MB
    unsigned short* kw  = qw + nTok * HEAD;              // 2 MB
    unsigned short* vtw = kw + nTok * HEAD;              // 2 MB

    qkv_proj<<<dim3(nTok / 16), dim3(256), 0, stream>>>(
        x, Wq, bq, Wk, bk, Wv, bv, qw, kw, vtw);

    flash_attn<<<dim3(512), dim3(256), 0, stream>>>(qw, kw, vtw, outp);
}

// Round 3
// 188.438 us; speedup vs baseline: 3.2757x; 1.4699x over previous
//
#include <hip/hip_runtime.h>

#define T_SEQ 4096
#define DMODEL 1024
#define HEAD 64
#define NBATCH 4

typedef __attribute__((ext_vector_type(8))) short bf16x8;
typedef __attribute__((ext_vector_type(4))) float f32x4;

__device__ __forceinline__ unsigned short f2bf(float f) {
    unsigned int b = __float_as_uint(f);
    unsigned int r = b + 0x7FFFu + ((b >> 16) & 1u);
    return (unsigned short)(r >> 16);
}

// ---------------- Kernel 0: W -> Wt[192][1024] bf16 (transpose + convert) ----
// grid = 48 blocks (3 matrices x 16 k-tiles), 256 threads.
__global__ __launch_bounds__(256) void prep_w(
    const float* __restrict__ Wq, const float* __restrict__ Wk,
    const float* __restrict__ Wv, unsigned short* __restrict__ Wtb)
{
    __shared__ unsigned short tl[64 * 72];
    const int bid = blockIdx.x;
    const int m   = bid >> 4;            // matrix 0..2
    const int k0  = (bid & 15) * 64;
    const float* W = (m == 0) ? Wq : (m == 1) ? Wk : Wv;
    const int t  = threadIdx.x;
    const int kr = t >> 2, qtr = t & 3;
#pragma unroll
    for (int i = 0; i < 4; ++i) {
        float4 wv4 = *(const float4*)&W[(k0 + kr) * 64 + qtr * 16 + i * 4];
        tl[(qtr * 16 + i * 4 + 0) * 72 + kr] = f2bf(wv4.x);
        tl[(qtr * 16 + i * 4 + 1) * 72 + kr] = f2bf(wv4.y);
        tl[(qtr * 16 + i * 4 + 2) * 72 + kr] = f2bf(wv4.z);
        tl[(qtr * 16 + i * 4 + 3) * 72 + kr] = f2bf(wv4.w);
    }
    __syncthreads();
#pragma unroll
    for (int c = 0; c < 2; ++c) {
        const int lin = c * 256 + t;
        const int n = lin >> 3, k8 = lin & 7;
        *(uint4*)&Wtb[((long)(m * 64 + n)) * 1024 + k0 + k8 * 8] =
            *(const uint4*)&tl[n * 72 + k8 * 8];
    }
}

// ---------------- Kernel 1: QKV projection as bf16 MFMA GEMM ----------------
// C[16384][192] = x[16384][1024] @ Wt^T, +bias. grid = 256 blocks, 256 threads.
// Block: 64 token rows. Wave w: n-tiles {3w,3w+1,3w+2}, all 4 m-tiles.
__global__ __launch_bounds__(256) void qkv_mfma(
    const float* __restrict__ x, const unsigned short* __restrict__ Wtb,
    const float* __restrict__ bq, const float* __restrict__ bk,
    const float* __restrict__ bv,
    unsigned short* __restrict__ qo, unsigned short* __restrict__ ko,
    unsigned short* __restrict__ vt)
{
    __shared__ __align__(16) unsigned short x_s[64 * 72];
    const int t    = threadIdx.x;
    const int lane = t & 63;
    const int l15  = lane & 15, quad = lane >> 4;
    const int w    = __builtin_amdgcn_readfirstlane(t >> 6);
    const long row0 = (long)blockIdx.x * 64;

    float bias[3];
#pragma unroll
    for (int ntl = 0; ntl < 3; ++ntl) {
        const int c = w * 48 + ntl * 16 + l15;
        bias[ntl] = (c < 64) ? bq[c] : (c < 128) ? bk[c - 64] : bv[c - 128];
    }
    f32x4 acc[4][3];
#pragma unroll
    for (int mt = 0; mt < 4; ++mt)
#pragma unroll
        for (int ntl = 0; ntl < 3; ++ntl)
            acc[mt][ntl] = (f32x4){bias[ntl], bias[ntl], bias[ntl], bias[ntl]};

    const int srow = t >> 2, sq = t & 3;
    const float* xp = x + (row0 + srow) * DMODEL + sq * 16;

    for (int kc = 0; kc < 16; ++kc) {
        // global loads first (no LDS dependency -> latency hides under staging)
        float4 xv[4];
#pragma unroll
        for (int i = 0; i < 4; ++i)
            xv[i] = *(const float4*)(xp + kc * 64 + i * 4);
        bf16x8 bfr[3][2];
#pragma unroll
        for (int ntl = 0; ntl < 3; ++ntl)
#pragma unroll
            for (int h = 0; h < 2; ++h)
                bfr[ntl][h] = *(const bf16x8*)&Wtb[((long)(w * 48 + ntl * 16 + l15)) * 1024
                                                   + kc * 64 + h * 32 + quad * 8];
        __syncthreads();   // previous iteration's compute done with x_s
        {
            unsigned short tmp[16];
#pragma unroll
            for (int i = 0; i < 4; ++i) {
                tmp[i * 4 + 0] = f2bf(xv[i].x);
                tmp[i * 4 + 1] = f2bf(xv[i].y);
                tmp[i * 4 + 2] = f2bf(xv[i].z);
                tmp[i * 4 + 3] = f2bf(xv[i].w);
            }
            *(uint4*)&x_s[srow * 72 + sq * 16]     = *(const uint4*)&tmp[0];
            *(uint4*)&x_s[srow * 72 + sq * 16 + 8] = *(const uint4*)&tmp[8];
        }
        __syncthreads();
#pragma unroll
        for (int mt = 0; mt < 4; ++mt) {
            bf16x8 a0 = *(const bf16x8*)&x_s[(mt * 16 + l15) * 72 + quad * 8];
            bf16x8 a1 = *(const bf16x8*)&x_s[(mt * 16 + l15) * 72 + 32 + quad * 8];
#pragma unroll
            for (int ntl = 0; ntl < 3; ++ntl) {
                acc[mt][ntl] = __builtin_amdgcn_mfma_f32_16x16x32_bf16(a0, bfr[ntl][0], acc[mt][ntl], 0, 0, 0);
                acc[mt][ntl] = __builtin_amdgcn_mfma_f32_16x16x32_bf16(a1, bfr[ntl][1], acc[mt][ntl], 0, 0, 0);
            }
        }
    }
    // epilogue: C/D layout col=l15, row=quad*4+r
#pragma unroll
    for (int mt = 0; mt < 4; ++mt)
#pragma unroll
        for (int ntl = 0; ntl < 3; ++ntl) {
            const int c = w * 48 + ntl * 16 + l15;
            const long tr0 = row0 + mt * 16 + quad * 4;
            if (c < 128) {
                unsigned short* dst = (c < 64) ? (qo + c) : (ko + (c - 64));
#pragma unroll
                for (int r = 0; r < 4; ++r)
                    dst[(tr0 + r) * HEAD] = f2bf(acc[mt][ntl][r]);
            } else {
                const int b = (int)(tr0 >> 12), tloc = (int)(tr0 & 4095);
                uint2 pv;
                pv.x = (unsigned)f2bf(acc[mt][ntl][0]) | ((unsigned)f2bf(acc[mt][ntl][1]) << 16);
                pv.y = (unsigned)f2bf(acc[mt][ntl][2]) | ((unsigned)f2bf(acc[mt][ntl][3]) << 16);
                *(uint2*)&vt[((long)(b * HEAD + (c - 128))) * T_SEQ + tloc] = pv;
            }
        }
}

// ---------------- Kernel 2: causal flash attention, bf16 MFMA ----------------
// (unchanged from round 2)
#define QT 32
#define SKT 128
#define KSS 72
#define VTS 136
#define QSS 72
#define PSS 72

__global__ __launch_bounds__(256) void flash_attn(
    const unsigned short* __restrict__ qg,
    const unsigned short* __restrict__ kg,
    const unsigned short* __restrict__ vtg,
    float* __restrict__ out)
{
    __shared__ __align__(16) unsigned short k_s[SKT * KSS];
    __shared__ __align__(16) unsigned short vt_s[HEAD * VTS];
    __shared__ __align__(16) unsigned short q_s[QT * QSS];
    __shared__ __align__(16) unsigned short p_s[4 * 16 * PSS];

    const int t     = threadIdx.x;
    const int n     = blockIdx.x;
    const int tile  = 127 - (n >> 2);
    const int b     = n & 3;
    const int qrow0 = tile * QT;
    const int lane  = t & 63;
    const int l15   = lane & 15;
    const int quad  = lane >> 4;
    const int w     = __builtin_amdgcn_readfirstlane(t >> 6);
    const int strip = w >> 1;
    const int half  = w & 1;
    const long bbase = (long)b * T_SEQ;
    const float scale = 0.03125f;

    {
        const int row = t >> 3, d8 = t & 7;
        *(uint4*)&q_s[row * QSS + d8 * 8] =
            *(const uint4*)&qg[(bbase + qrow0 + row) * HEAD + d8 * 8];
    }
    __syncthreads();

    bf16x8 aq0 = *(const bf16x8*)&q_s[(strip * 16 + l15) * QSS + quad * 8];
    bf16x8 aq1 = *(const bf16x8*)&q_s[(strip * 16 + l15) * QSS + 32 + quad * 8];

    f32x4 o[4];
#pragma unroll
    for (int dt = 0; dt < 4; ++dt) o[dt] = (f32x4){0.f, 0.f, 0.f, 0.f};
    float mrun[4], lrun[4];
#pragma unroll
    for (int r = 0; r < 4; ++r) { mrun[r] = -1e30f; lrun[r] = 0.f; }

    const int nkt = (qrow0 + QT + SKT - 1) / SKT;
    const int qrow_base = qrow0 + strip * 16;
    unsigned short* ps = p_s + w * 16 * PSS;

    for (int kt = 0; kt < nkt; ++kt) {
        const int key0 = kt * SKT;
        __syncthreads();
#pragma unroll
        for (int c = 0; c < 4; ++c) {
            const int lin = c * 256 + t;
            const int row = lin >> 3, d8 = lin & 7;
            int gk = key0 + row; if (gk > T_SEQ - 1) gk = T_SEQ - 1;
            *(uint4*)&k_s[row * KSS + d8 * 8] =
                *(const uint4*)&kg[(bbase + gk) * HEAD + d8 * 8];
        }
#pragma unroll
        for (int c = 0; c < 4; ++c) {
            const int lin = c * 256 + t;
            const int dim = lin >> 4, k8 = lin & 15;
            int koff = key0 + k8 * 8; if (koff > T_SEQ - 8) koff = T_SEQ - 8;
            *(uint4*)&vt_s[dim * VTS + k8 * 8] =
                *(const uint4*)&vtg[((long)(b * HEAD + dim)) * T_SEQ + koff];
        }
        __syncthreads();

        const int keyw = key0 + half * 64;
        if (keyw <= qrow0 + QT - 1) {
            f32x4 s[4];
#pragma unroll
            for (int nt = 0; nt < 4; ++nt) s[nt] = (f32x4){0.f, 0.f, 0.f, 0.f};
#pragma unroll
            for (int nt = 0; nt < 4; ++nt) {
                bf16x8 bk0 = *(const bf16x8*)&k_s[(half * 64 + nt * 16 + l15) * KSS + quad * 8];
                bf16x8 bk1 = *(const bf16x8*)&k_s[(half * 64 + nt * 16 + l15) * KSS + 32 + quad * 8];
                s[nt] = __builtin_amdgcn_mfma_f32_16x16x32_bf16(aq0, bk0, s[nt], 0, 0, 0);
                s[nt] = __builtin_amdgcn_mfma_f32_16x16x32_bf16(aq1, bk1, s[nt], 0, 0, 0);
            }
            float mt[4] = {-1e30f, -1e30f, -1e30f, -1e30f};
#pragma unroll
            for (int nt = 0; nt < 4; ++nt)
#pragma unroll
                for (int r = 0; r < 4; ++r) {
                    const int key  = keyw + nt * 16 + l15;
                    const int qrow = qrow_base + quad * 4 + r;
                    const float val = (key <= qrow) ? s[nt][r] * scale : -1e30f;
                    s[nt][r] = val;
                    mt[r] = fmaxf(mt[r], val);
                }
#pragma unroll
            for (int msk = 1; msk <= 8; msk <<= 1)
#pragma unroll
                for (int r = 0; r < 4; ++r)
                    mt[r] = fmaxf(mt[r], __shfl_xor(mt[r], msk));
            float al[4], psum[4];
#pragma unroll
            for (int r = 0; r < 4; ++r) {
                const float mn = fmaxf(mrun[r], mt[r]);
                al[r] = __expf(mrun[r] - mn);
                mrun[r] = mn;
                psum[r] = 0.f;
            }
#pragma unroll
            for (int nt = 0; nt < 4; ++nt)
#pragma unroll
                for (int r = 0; r < 4; ++r) {
                    const float p = (s[nt][r] > -0.9e30f) ? __expf(s[nt][r] - mrun[r]) : 0.f;
                    psum[r] += p;
                    ps[(quad * 4 + r) * PSS + nt * 16 + l15] = f2bf(p);
                }
#pragma unroll
            for (int msk = 1; msk <= 8; msk <<= 1)
#pragma unroll
                for (int r = 0; r < 4; ++r)
                    psum[r] += __shfl_xor(psum[r], msk);
#pragma unroll
            for (int r = 0; r < 4; ++r) lrun[r] = lrun[r] * al[r] + psum[r];
#pragma unroll
            for (int dt = 0; dt < 4; ++dt)
#pragma unroll
                for (int r = 0; r < 4; ++r) o[dt][r] *= al[r];
            __builtin_amdgcn_wave_barrier();
            bf16x8 ap0 = *(const bf16x8*)&ps[l15 * PSS + quad * 8];
            bf16x8 ap1 = *(const bf16x8*)&ps[l15 * PSS + 32 + quad * 8];
#pragma unroll
            for (int dt = 0; dt < 4; ++dt) {
                bf16x8 bv0 = *(const bf16x8*)&vt_s[(dt * 16 + l15) * VTS + half * 64 + quad * 8];
                bf16x8 bv1 = *(const bf16x8*)&vt_s[(dt * 16 + l15) * VTS + half * 64 + 32 + quad * 8];
                o[dt] = __builtin_amdgcn_mfma_f32_16x16x32_bf16(ap0, bv0, o[dt], 0, 0, 0);
                o[dt] = __builtin_amdgcn_mfma_f32_16x16x32_bf16(ap1, bv1, o[dt], 0, 0, 0);
            }
        }
    }

    __syncthreads();
    float* o_l  = (float*)k_s;
    float* ml_l = (float*)vt_s;
    if (half == 1) {
#pragma unroll
        for (int dt = 0; dt < 4; ++dt)
#pragma unroll
            for (int r = 0; r < 4; ++r)
                o_l[(strip * 16 + quad * 4 + r) * HEAD + dt * 16 + l15] = o[dt][r];
        if (l15 == 0)
#pragma unroll
            for (int r = 0; r < 4; ++r) {
                ml_l[strip * 16 + quad * 4 + r]      = mrun[r];
                ml_l[32 + strip * 16 + quad * 4 + r] = lrun[r];
            }
    }
    __syncthreads();
    if (half == 0) {
        float w1s[4], w2s[4];
#pragma unroll
        for (int r = 0; r < 4; ++r) {
            const int rr = strip * 16 + quad * 4 + r;
            const float m2 = ml_l[rr], l2 = ml_l[32 + rr];
            const float M  = fmaxf(mrun[r], m2);
            const float w1 = __expf(mrun[r] - M), w2 = __expf(m2 - M);
            const float inv = 1.f / (w1 * lrun[r] + w2 * l2);
            w1s[r] = w1 * inv; w2s[r] = w2 * inv;
        }
#pragma unroll
        for (int dt = 0; dt < 4; ++dt)
#pragma unroll
            for (int r = 0; r < 4; ++r) {
                const int rr = strip * 16 + quad * 4 + r;
                const float o2 = o_l[rr * HEAD + dt * 16 + l15];
                out[(bbase + qrow0 + rr) * HEAD + dt * 16 + l15] =
                    o[dt][r] * w1s[r] + o2 * w2s[r];
            }
    }
}

extern "C" void kernel_launch(void* const* d_in, const int* in_sizes, int n_in,
                              void* d_out, int out_size, void* d_ws, size_t ws_size,
                              hipStream_t stream) {
    const float* x  = (const float*)d_in[0];
    const float* Wq = (const float*)d_in[1];
    const float* bq = (const float*)d_in[2];
    const float* Wk = (const float*)d_in[3];
    const float* bk = (const float*)d_in[4];
    const float* Wv = (const float*)d_in[5];
    const float* bv = (const float*)d_in[6];
    float* outp = (float*)d_out;

    const long nTok = (long)NBATCH * T_SEQ;                  // 16384
    unsigned short* wtb = (unsigned short*)d_ws;             // 384 KB
    unsigned short* qw  = wtb + (long)192 * 1024;            // 2 MB
    unsigned short* kw  = qw + nTok * HEAD;                  // 2 MB
    unsigned short* vtw = kw + nTok * HEAD;                  // 2 MB

    prep_w<<<dim3(48), dim3(256), 0, stream>>>(Wq, Wk, Wv, wtb);
    qkv_mfma<<<dim3(256), dim3(256), 0, stream>>>(
        x, wtb, bq, bk, bv, qw, kw, vtw);
    flash_attn<<<dim3(512), dim3(256), 0, stream>>>(qw, kw, vtw, outp);
}

// Round 4
// 177.275 us; speedup vs baseline: 3.4820x; 1.0630x over previous
//
#include <hip/hip_runtime.h>
#include <hip/hip_bf16.h>
#include <hip/hip_fp16.h>

#define T_SEQ 4096
#define DMODEL 1024
#define HEAD 64
#define NBATCH 4
#define NSEG 576              // segments per batch
#define S2LOG 0.04508422f     // (1/sqrt(1024)) * log2(e), folded into q

typedef __attribute__((ext_vector_type(8))) short bf16x8;
typedef __attribute__((ext_vector_type(4))) float f32x4;

__device__ __forceinline__ unsigned short f2bf(float f) {
    unsigned int b = __float_as_uint(f);
    unsigned int r = b + 0x7FFFu + ((b >> 16) & 1u);
    return (unsigned short)(r >> 16);
}
__device__ __forceinline__ unsigned int pk_bf16(float a, float b) {
    __hip_bfloat162 h = __float22bfloat162_rn(make_float2(a, b));
    unsigned int u; __builtin_memcpy(&u, &h, 4); return u;
}

// ---------------- Kernel 0: W -> Wt[192][1024] bf16 (transpose + convert) ----
__global__ __launch_bounds__(256) void prep_w(
    const float* __restrict__ Wq, const float* __restrict__ Wk,
    const float* __restrict__ Wv, unsigned short* __restrict__ Wtb)
{
    __shared__ unsigned short tl[64 * 72];
    const int bid = blockIdx.x;
    const int m   = bid >> 4;
    const int k0  = (bid & 15) * 64;
    const float* W = (m == 0) ? Wq : (m == 1) ? Wk : Wv;
    const int t  = threadIdx.x;
    const int kr = t >> 2, qtr = t & 3;
#pragma unroll
    for (int i = 0; i < 4; ++i) {
        float4 wv4 = *(const float4*)&W[(k0 + kr) * 64 + qtr * 16 + i * 4];
        tl[(qtr * 16 + i * 4 + 0) * 72 + kr] = f2bf(wv4.x);
        tl[(qtr * 16 + i * 4 + 1) * 72 + kr] = f2bf(wv4.y);
        tl[(qtr * 16 + i * 4 + 2) * 72 + kr] = f2bf(wv4.z);
        tl[(qtr * 16 + i * 4 + 3) * 72 + kr] = f2bf(wv4.w);
    }
    __syncthreads();
#pragma unroll
    for (int c = 0; c < 2; ++c) {
        const int lin = c * 256 + t;
        const int n = lin >> 3, k8 = lin & 7;
        *(uint4*)&Wtb[((long)(m * 64 + n)) * 1024 + k0 + k8 * 8] =
            *(const uint4*)&tl[n * 72 + k8 * 8];
    }
}

// ---------------- Kernel 1: QKV projection, double-buffered bf16 MFMA -------
// 512 blocks x 32 rows. q is pre-scaled by S2LOG for exp2-based softmax.
__global__ __launch_bounds__(256, 2) void qkv_mfma(
    const float* __restrict__ x, const unsigned short* __restrict__ Wtb,
    const float* __restrict__ bq, const float* __restrict__ bk,
    const float* __restrict__ bv,
    unsigned short* __restrict__ qo, unsigned short* __restrict__ ko,
    unsigned short* __restrict__ vt)
{
    __shared__ __align__(16) unsigned short x_s[2][32 * 136];
    const int t    = threadIdx.x;
    const int lane = t & 63;
    const int l15  = lane & 15, quad = lane >> 4;
    const int w    = __builtin_amdgcn_readfirstlane(t >> 6);
    const long row0 = (long)blockIdx.x * 32;

    float bias[3];
#pragma unroll
    for (int ntl = 0; ntl < 3; ++ntl) {
        const int c = w * 48 + ntl * 16 + l15;
        bias[ntl] = (c < 64) ? bq[c] : (c < 128) ? bk[c - 64] : bv[c - 128];
    }
    f32x4 acc[2][3];
#pragma unroll
    for (int mt = 0; mt < 2; ++mt)
#pragma unroll
        for (int ntl = 0; ntl < 3; ++ntl)
            acc[mt][ntl] = (f32x4){bias[ntl], bias[ntl], bias[ntl], bias[ntl]};

    const int srow = t >> 3, sseg = t & 7;
    const float* xp = x + (row0 + srow) * DMODEL + sseg * 16;

    // prologue: stage 0
    float4 xv[4];
#pragma unroll
    for (int i = 0; i < 4; ++i) xv[i] = *(const float4*)(xp + i * 4);
    {
        unsigned int pk_[8];
#pragma unroll
        for (int i = 0; i < 4; ++i) {
            pk_[i * 2]     = pk_bf16(xv[i].x, xv[i].y);
            pk_[i * 2 + 1] = pk_bf16(xv[i].z, xv[i].w);
        }
        *(uint4*)&x_s[0][srow * 136 + sseg * 16]     = *(const uint4*)&pk_[0];
        *(uint4*)&x_s[0][srow * 136 + sseg * 16 + 8] = *(const uint4*)&pk_[4];
    }
    __syncthreads();

    for (int sg = 0; sg < 8; ++sg) {
        if (sg + 1 < 8)
#pragma unroll
            for (int i = 0; i < 4; ++i)
                xv[i] = *(const float4*)(xp + (sg + 1) * 128 + i * 4);
        bf16x8 wf[3][4];
#pragma unroll
        for (int ntl = 0; ntl < 3; ++ntl)
#pragma unroll
            for (int kq = 0; kq < 4; ++kq)
                wf[ntl][kq] = *(const bf16x8*)&Wtb[((long)(w * 48 + ntl * 16 + l15)) * 1024
                                                   + sg * 128 + kq * 32 + quad * 8];
#pragma unroll
        for (int mt = 0; mt < 2; ++mt)
#pragma unroll
            for (int kq = 0; kq < 4; ++kq) {
                bf16x8 a = *(const bf16x8*)&x_s[sg & 1][(mt * 16 + l15) * 136 + kq * 32 + quad * 8];
#pragma unroll
                for (int ntl = 0; ntl < 3; ++ntl)
                    acc[mt][ntl] = __builtin_amdgcn_mfma_f32_16x16x32_bf16(a, wf[ntl][kq], acc[mt][ntl], 0, 0, 0);
            }
        if (sg + 1 < 8) {
            unsigned int pk_[8];
#pragma unroll
            for (int i = 0; i < 4; ++i) {
                pk_[i * 2]     = pk_bf16(xv[i].x, xv[i].y);
                pk_[i * 2 + 1] = pk_bf16(xv[i].z, xv[i].w);
            }
            *(uint4*)&x_s[(sg + 1) & 1][srow * 136 + sseg * 16]     = *(const uint4*)&pk_[0];
            *(uint4*)&x_s[(sg + 1) & 1][srow * 136 + sseg * 16 + 8] = *(const uint4*)&pk_[4];
        }
        __syncthreads();
    }
    // epilogue: C/D col=l15, row=quad*4+r
#pragma unroll
    for (int mt = 0; mt < 2; ++mt)
#pragma unroll
        for (int ntl = 0; ntl < 3; ++ntl) {
            const int c = w * 48 + ntl * 16 + l15;
            const long tr0 = row0 + mt * 16 + quad * 4;
            if (c < 64) {
#pragma unroll
                for (int r = 0; r < 4; ++r)
                    qo[(tr0 + r) * HEAD + c] = f2bf(acc[mt][ntl][r] * S2LOG);
            } else if (c < 128) {
#pragma unroll
                for (int r = 0; r < 4; ++r)
                    ko[(tr0 + r) * HEAD + (c - 64)] = f2bf(acc[mt][ntl][r]);
            } else {
                const int b = (int)(tr0 >> 12), tloc = (int)(tr0 & 4095);
                uint2 pv;
                pv.x = pk_bf16(acc[mt][ntl][0], acc[mt][ntl][1]);
                pv.y = pk_bf16(acc[mt][ntl][2], acc[mt][ntl][3]);
                *(uint2*)&vt[((long)(b * HEAD + (c - 128))) * T_SEQ + tloc] = pv;
            }
        }
}

// ---------------- Kernel 2: flash attention, split-K, barrier-free waves ----
// 576 blocks x 4 waves; wave wv handles segment sid=575-blockIdx for batch wv.
// S^T = K Q^T (lane = q-row), O^T = V^T P^T. No __syncthreads anywhere.
__global__ __launch_bounds__(256, 3) void flash_seg(
    const unsigned short* __restrict__ qg,
    const unsigned short* __restrict__ kg,
    const unsigned short* __restrict__ vtg,
    __half* __restrict__ opart, float* __restrict__ ml)
{
    __shared__ __align__(16) unsigned short p_s[4][32 * 72];
    const int t0   = threadIdx.x;
    const int lane = t0 & 63;
    const int l15  = lane & 15, quad = lane >> 4;
    const int wv   = __builtin_amdgcn_readfirstlane(t0 >> 6);

    // block-uniform segment decode: sid -> (tier kk, tile t, sub-segment si)
    const int sid = (NSEG - 1) - (int)blockIdx.x;
    int kk = 0, pref = 0;
#pragma unroll
    for (int i = 0; i < 7; ++i) {
        const int cnt = 16 * (kk + 1);
        if (sid >= pref + cnt) { pref += cnt; ++kk; }
    }
    const int S   = kk + 1;
    const int rem = sid - pref;
    const int t   = kk * 16 + rem / S;
    const int si  = rem % S;
    const int r0  = t * 32;
    const int nck = (t + 2) >> 1;               // 64-key chunks in this tile
    const int c0  = (si * nck) / S, c1 = ((si + 1) * nck) / S;
    const int b   = wv;
    const long bbase = (long)b * T_SEQ;
    const int gidx = b * NSEG + sid;

    bf16x8 qf[2][2];
#pragma unroll
    for (int s = 0; s < 2; ++s)
#pragma unroll
        for (int h = 0; h < 2; ++h)
            qf[s][h] = *(const bf16x8*)&qg[(bbase + r0 + s * 16 + l15) * HEAD + h * 32 + quad * 8];

    f32x4 o[2][4];
#pragma unroll
    for (int s = 0; s < 2; ++s)
#pragma unroll
        for (int dt = 0; dt < 4; ++dt) o[s][dt] = (f32x4){0.f, 0.f, 0.f, 0.f};
    float mrun[2] = {-30000.f, -30000.f}, lrun[2] = {0.f, 0.f};

    unsigned short* ps = p_s[wv];

    for (int c = c0; c < c1; ++c) {
        const int key0 = c * 64;
        // K fragments straight from global (L2-hot)
        bf16x8 kf[4][2];
#pragma unroll
        for (int mt = 0; mt < 4; ++mt) {
            int krow = key0 + mt * 16 + l15; if (krow > T_SEQ - 1) krow = T_SEQ - 1;
            const unsigned short* kp = &kg[(bbase + krow) * HEAD + quad * 8];
            kf[mt][0] = *(const bf16x8*)kp;
            kf[mt][1] = *(const bf16x8*)(kp + 32);
        }
        f32x4 st[2][4];
#pragma unroll
        for (int s = 0; s < 2; ++s)
#pragma unroll
            for (int mt = 0; mt < 4; ++mt) {
                f32x4 z = (f32x4){0.f, 0.f, 0.f, 0.f};
                z = __builtin_amdgcn_mfma_f32_16x16x32_bf16(kf[mt][0], qf[s][0], z, 0, 0, 0);
                st[s][mt] = __builtin_amdgcn_mfma_f32_16x16x32_bf16(kf[mt][1], qf[s][1], z, 0, 0, 0);
            }
        // V fragments (issued early; consumed after softmax)
        bf16x8 vf[4][2];
#pragma unroll
        for (int dt = 0; dt < 4; ++dt)
#pragma unroll
            for (int g = 0; g < 2; ++g) {
                int kof = key0 + g * 32 + quad * 8; if (kof > T_SEQ - 8) kof = T_SEQ - 8;
                vf[dt][g] = *(const bf16x8*)&vtg[((long)(b * HEAD + dt * 16 + l15)) * T_SEQ + kof];
            }
        // causal mask (only near the diagonal; wave-uniform branch)
        if (key0 + 63 > r0) {
#pragma unroll
            for (int s = 0; s < 2; ++s) {
                const int row = r0 + s * 16 + l15;
#pragma unroll
                for (int mt = 0; mt < 4; ++mt)
#pragma unroll
                    for (int r = 0; r < 4; ++r) {
                        const int key = key0 + mt * 16 + quad * 4 + r;
                        st[s][mt][r] = (key <= row) ? st[s][mt][r] : -30000.f;
                    }
            }
        }
        // online softmax, lane = q-row (state fully lane-local)
#pragma unroll
        for (int s = 0; s < 2; ++s) {
            float mx = st[s][0][0];
#pragma unroll
            for (int mt = 0; mt < 4; ++mt)
#pragma unroll
                for (int r = 0; r < 4; ++r) mx = fmaxf(mx, st[s][mt][r]);
            mx = fmaxf(mx, __shfl_xor(mx, 16));
            mx = fmaxf(mx, __shfl_xor(mx, 32));
            const float mn = fmaxf(mrun[s], mx);
            const float al = exp2f(mrun[s] - mn);
            mrun[s] = mn;
            float psum = 0.f;
#pragma unroll
            for (int mt = 0; mt < 4; ++mt) {
                float e0 = exp2f(st[s][mt][0] - mn), e1 = exp2f(st[s][mt][1] - mn);
                float e2 = exp2f(st[s][mt][2] - mn), e3 = exp2f(st[s][mt][3] - mn);
                psum += (e0 + e1) + (e2 + e3);
                *(unsigned int*)&ps[(s * 16 + l15) * 72 + mt * 16 + quad * 4]     = pk_bf16(e0, e1);
                *(unsigned int*)&ps[(s * 16 + l15) * 72 + mt * 16 + quad * 4 + 2] = pk_bf16(e2, e3);
            }
            psum += __shfl_xor(psum, 16);
            psum += __shfl_xor(psum, 32);
            lrun[s] = lrun[s] * al + psum;
#pragma unroll
            for (int dt = 0; dt < 4; ++dt)
#pragma unroll
                for (int r = 0; r < 4; ++r) o[s][dt][r] *= al;
        }
        __builtin_amdgcn_wave_barrier();
        // P^T fragments (per-wave LDS; DS is in-order within a wave)
        bf16x8 pf[2][2];
#pragma unroll
        for (int s = 0; s < 2; ++s)
#pragma unroll
            for (int g = 0; g < 2; ++g)
                pf[s][g] = *(const bf16x8*)&ps[(s * 16 + l15) * 72 + g * 32 + quad * 8];
        __builtin_amdgcn_wave_barrier();
#pragma unroll
        for (int s = 0; s < 2; ++s)
#pragma unroll
            for (int dt = 0; dt < 4; ++dt) {
                o[s][dt] = __builtin_amdgcn_mfma_f32_16x16x32_bf16(vf[dt][0], pf[s][0], o[s][dt], 0, 0, 0);
                o[s][dt] = __builtin_amdgcn_mfma_f32_16x16x32_bf16(vf[dt][1], pf[s][1], o[s][dt], 0, 0, 0);
            }
    }
    // write partial: O^T frag -> opart[gidx][row][d] (fp16), m/l lane-local
    __half* op = opart + (long)gidx * 2048;
#pragma unroll
    for (int s = 0; s < 2; ++s) {
#pragma unroll
        for (int dt = 0; dt < 4; ++dt) {
            __half2 h0 = __floats2half2_rn(o[s][dt][0], o[s][dt][1]);
            __half2 h1 = __floats2half2_rn(o[s][dt][2], o[s][dt][3]);
            uint2 u; __builtin_memcpy(&u.x, &h0, 4); __builtin_memcpy(&u.y, &h1, 4);
            *(uint2*)&op[(s * 16 + l15) * HEAD + dt * 16 + quad * 4] = u;
        }
        if (quad == 0) {
            ml[(long)gidx * 64 + s * 16 + l15]      = mrun[s];
            ml[(long)gidx * 64 + 32 + s * 16 + l15] = lrun[s];
        }
    }
}

// ---------------- Kernel 3: merge split-K partials ----------------
// 512 blocks (one per (batch, 32-row tile)); thread: row = tid>>3, 8 cols.
__global__ __launch_bounds__(256) void merge_seg(
    const __half* __restrict__ opart, const float* __restrict__ ml,
    float* __restrict__ out)
{
    const int bid = blockIdx.x;
    const int t = bid & 127, b = bid >> 7;
    const int kk = t >> 4, S = kk + 1;
    const int base_sid = 8 * kk * (kk + 1) + (t & 15) * S;
    const int tid = threadIdx.x;
    const int row = tid >> 3, col0 = (tid & 7) * 8;

    float m[8], l[8], M = -30000.f;
    for (int si = 0; si < S; ++si) {
        const long g = (long)(b * NSEG + base_sid + si);
        m[si] = ml[g * 64 + row];
        l[si] = ml[g * 64 + 32 + row];
        M = fmaxf(M, m[si]);
    }
    float acc[8];
#pragma unroll
    for (int j = 0; j < 8; ++j) acc[j] = 0.f;
    float L = 0.f;
    for (int si = 0; si < S; ++si) {
        const float wgt = exp2f(m[si] - M);
        L += wgt * l[si];
        const __half* op = opart + (long)(b * NSEG + base_sid + si) * 2048 + row * 64 + col0;
        uint4 u = *(const uint4*)op;
        __half2 h01, h23, h45, h67;
        __builtin_memcpy(&h01, &u.x, 4); __builtin_memcpy(&h23, &u.y, 4);
        __builtin_memcpy(&h45, &u.z, 4); __builtin_memcpy(&h67, &u.w, 4);
        float2 f01 = __half22float2(h01), f23 = __half22float2(h23);
        float2 f45 = __half22float2(h45), f67 = __half22float2(h67);
        acc[0] += wgt * f01.x; acc[1] += wgt * f01.y;
        acc[2] += wgt * f23.x; acc[3] += wgt * f23.y;
        acc[4] += wgt * f45.x; acc[5] += wgt * f45.y;
        acc[6] += wgt * f67.x; acc[7] += wgt * f67.y;
    }
    const float inv = 1.f / L;
    float4 o0 = {acc[0] * inv, acc[1] * inv, acc[2] * inv, acc[3] * inv};
    float4 o1 = {acc[4] * inv, acc[5] * inv, acc[6] * inv, acc[7] * inv};
    float* dst = out + ((long)(b * T_SEQ + t * 32 + row)) * HEAD + col0;
    *(float4*)dst = o0;
    *(float4*)(dst + 4) = o1;
}

extern "C" void kernel_launch(void* const* d_in, const int* in_sizes, int n_in,
                              void* d_out, int out_size, void* d_ws, size_t ws_size,
                              hipStream_t stream) {
    const float* x  = (const float*)d_in[0];
    const float* Wq = (const float*)d_in[1];
    const float* bq = (const float*)d_in[2];
    const float* Wk = (const float*)d_in[3];
    const float* bk = (const float*)d_in[4];
    const float* Wv = (const float*)d_in[5];
    const float* bv = (const float*)d_in[6];
    float* outp = (float*)d_out;

    char* wsb = (char*)d_ws;
    unsigned short* wtb = (unsigned short*)(wsb);                  // 384 KB
    unsigned short* qw  = (unsigned short*)(wsb + 393216);         // 2 MB
    unsigned short* kw  = (unsigned short*)(wsb + 2490368);        // 2 MB
    unsigned short* vtw = (unsigned short*)(wsb + 4587520);        // 2 MB
    __half* opart       = (__half*)(wsb + 6684672);                // 9.4 MB
    float*  mlp         = (float*)(wsb + 16121856);                // 0.6 MB

    prep_w<<<dim3(48), dim3(256), 0, stream>>>(Wq, Wk, Wv, wtb);
    qkv_mfma<<<dim3(512), dim3(256), 0, stream>>>(
        x, wtb, bq, bk, bv, qw, kw, vtw);
    flash_seg<<<dim3(NSEG), dim3(256), 0, stream>>>(qw, kw, vtw, opart, mlp);
    merge_seg<<<dim3(512), dim3(256), 0, stream>>>(opart, mlp, outp);
}